// Round 9
// baseline (73.137 us; speedup 1.0000x reference)
//
#include <hip/hip_runtime.h>

// DarcyLoss: B=4096, C=2, H=W=64. Inputs (f32): model_out, target, x0_hat [B,2,64,64], var [B].
// loss = mean((mo-tg)^2) + mean_b( min(0.5*r_b^2/var_b, 27.6310211159) )
// r_b = (sum(eq0)+sum(bc)) / (64*64*3);  source f_s sums to 0 -> omitted.
//
// R9 = R8 with a deeper row pipeline: 16-slot rolling window (&15 static
// indexing -> registers), preload rows 0..9, prefetch distance 10
// -> ~10 p + 10 q loads (5 KB/wave) outstanding. 16 waves/CU x 5 KB ~= 80 KB/CU
// in flight. Grid caps occupancy at 4 waves/SIMD, so VGPR growth to ~80 is free.
// mo/tg streaming fused (nontemporal float4, iters 1..32). No LDS, no barriers.

#define NB 4096
#define HW 4096          // 64*64
#define CHW 8192         // 2*64*64

typedef float vf4 __attribute__((ext_vector_type(4)));

__device__ __forceinline__ void hderiv2(float v, int j, float& d1, float& d11) {
    constexpr float INV2D = 31.5f, INVD2 = 3969.0f;
    float vm = __shfl(v, (j + 63) & 63);
    float vp = __shfl(v, (j + 1) & 63);
    float v2 = __shfl(v, (j == 0) ? 2 : 61);
    float v3 = __shfl(v, (j == 0) ? 3 : 60);
    d1  = (vp - vm) * INV2D;
    d11 = (vp - 2.0f * v + vm) * INVD2;
    if (j == 0)  { d1 = (-3.0f * v + 4.0f * vp - v2) * INV2D;
                   d11 = (2.0f * v - 5.0f * vp + 4.0f * v2 - v3) * INVD2; }
    if (j == 63) { d1 = ( 3.0f * v - 4.0f * vm + v2) * INV2D;
                   d11 = (2.0f * v - 5.0f * vm + 4.0f * v2 - v3) * INVD2; }
}

__device__ __forceinline__ float hderiv1(float v, int j) {
    constexpr float INV2D = 31.5f;
    float vm = __shfl(v, (j + 63) & 63);
    float vp = __shfl(v, (j + 1) & 63);
    float v2 = __shfl(v, (j == 0) ? 2 : 61);
    float d = (vp - vm) * INV2D;
    if (j == 0)  d = (-3.0f * v + 4.0f * vp - v2) * INV2D;
    if (j == 63) d = ( 3.0f * v - 4.0f * vm + v2) * INV2D;
    return d;
}

__global__ __launch_bounds__(256, 4) void darcy_wave_kernel(
    const float* __restrict__ mo, const float* __restrict__ tg,
    const float* __restrict__ x0, const float* __restrict__ var,
    float* __restrict__ ws_res, float* __restrict__ ws_d)
{
    constexpr float INV2D = 31.5f;
    constexpr float INVD2 = 3969.0f;
    constexpr float CLAMP = 27.6310211159f;

    const int wv = threadIdx.x >> 6;
    const int j  = threadIdx.x & 63;
    const int b  = blockIdx.x * 4 + wv;

    const float* pb = x0 + (size_t)b * CHW;        // p    plane
    const float* qb = pb + HW;                     // perm plane
    const vf4*   m4 = (const vf4*)(mo + (size_t)b * CHW);   // 2048 f4
    const vf4*   g4 = (const vf4*)(tg + (size_t)b * CHW);

    float rsum = 0.0f, dsum = 0.0f;

    // ---- 16-slot register row pipeline; preload rows 0..9 ----
    float ps[16], qs[16];
    #pragma unroll
    for (int k = 0; k < 10; ++k) {
        ps[k] = pb[(k << 6) + j];
        qs[k] = qb[(k << 6) + j];
    }

    // ---- row i = 0 (one-sided vertical), uses rows 0..3 ----
    {
        float pd1, pd11;
        hderiv2(ps[0], j, pd1, pd11);
        float qd1 = hderiv1(qs[0], j);
        float pd0  = (-3.0f * ps[0] + 4.0f * ps[1] - ps[2]) * INV2D;
        float pd00 = (2.0f * ps[0] - 5.0f * ps[1] + 4.0f * ps[2] - ps[3]) * INVD2;
        float qd0  = (-3.0f * qs[0] + 4.0f * qs[1] - qs[2]) * INV2D;
        rsum += -qs[0] * (pd00 + pd11) - qd0 * pd0 - qd1 * pd1 - pd0;   // bc(i=0)
        rsum += (j == 0) ? pd1 : 0.0f;
        rsum -= (j == 63) ? pd1 : 0.0f;
    }

    // ---- rows 1..62, fully unrolled; prefetch row i+10 at iter i ----
    #pragma unroll
    for (int i = 1; i <= 62; ++i) {
        if (i + 10 <= 63) {
            ps[(i + 10) & 15] = pb[((i + 10) << 6) + j];
            qs[(i + 10) & 15] = qb[((i + 10) << 6) + j];
        }
        if (i <= 32) {   // fused data-loss chunk i-1 (nontemporal: zero reuse)
            vf4 a = __builtin_nontemporal_load(m4 + ((i - 1) << 6) + j);
            vf4 c = __builtin_nontemporal_load(g4 + ((i - 1) << 6) + j);
            vf4 e = a - c;
            dsum += e.x * e.x + e.y * e.y + e.z * e.z + e.w * e.w;
        }

        const float pm = ps[(i - 1) & 15], pc = ps[i & 15], pp = ps[(i + 1) & 15];
        const float qm = qs[(i - 1) & 15], qc = qs[i & 15], qp = qs[(i + 1) & 15];

        float pd1, pd11;
        hderiv2(pc, j, pd1, pd11);
        float qd1 = hderiv1(qc, j);
        float pd0  = (pp - pm) * INV2D;
        float pd00 = (pp - 2.0f * pc + pm) * INVD2;
        float qd0  = (qp - qm) * INV2D;
        rsum += -qc * (pd00 + pd11) - qd0 * pd0 - qd1 * pd1;
        rsum += (j == 0) ? pd1 : 0.0f;
        rsum -= (j == 63) ? pd1 : 0.0f;
    }

    // ---- row i = 63 (one-sided vertical); rows 60..63 = slots 12..15 ----
    {
        const float p63 = ps[15], p62 = ps[14], p61 = ps[13], p60 = ps[12];
        const float q63 = qs[15], q62 = qs[14], q61 = qs[13];
        float pd1, pd11;
        hderiv2(p63, j, pd1, pd11);
        float qd1 = hderiv1(q63, j);
        float pd0  = (3.0f * p63 - 4.0f * p62 + p61) * INV2D;
        float pd00 = (2.0f * p63 - 5.0f * p62 + 4.0f * p61 - p60) * INVD2;
        float qd0  = (3.0f * q63 - 4.0f * q62 + q61) * INV2D;
        rsum += -q63 * (pd00 + pd11) - qd0 * pd0 - qd1 * pd1 + pd0;   // bc(i=63)
        rsum += (j == 0) ? pd1 : 0.0f;
        rsum -= (j == 63) ? pd1 : 0.0f;
    }

    // ---- per-wave reduction (wave == batch) ----
    #pragma unroll
    for (int off = 32; off > 0; off >>= 1) {
        rsum += __shfl_down(rsum, off);
        dsum += __shfl_down(dsum, off);
    }
    if (j == 0) {
        const float r = rsum * (1.0f / (64.0f * 64.0f * 3.0f));
        float res = 0.5f * r * r / var[b];
        ws_res[b] = fminf(res, CLAMP);
        ws_d[b]   = dsum;
    }
}

__global__ __launch_bounds__(256) void darcy_final_kernel(
    const float* __restrict__ ws_res, const float* __restrict__ ws_d,
    float* __restrict__ out)
{
    const int t = threadIdx.x;
    double rs = 0.0, ds = 0.0;
    for (int i = t; i < NB; i += 256) {
        rs += (double)ws_res[i];
        ds += (double)ws_d[i];
    }
    #pragma unroll
    for (int off = 32; off > 0; off >>= 1) {
        rs += __shfl_down(rs, off);
        ds += __shfl_down(ds, off);
    }
    __shared__ double red[8];
    const int wid = t >> 6, lane = t & 63;
    if (lane == 0) { red[wid] = rs; red[4 + wid] = ds; }
    __syncthreads();
    if (t == 0) {
        const double R  = red[0] + red[1] + red[2] + red[3];
        const double Dd = red[4] + red[5] + red[6] + red[7];
        out[0] = (float)(Dd / ((double)NB * (double)CHW) + R / (double)NB);
    }
}

extern "C" void kernel_launch(void* const* d_in, const int* in_sizes, int n_in,
                              void* d_out, int out_size, void* d_ws, size_t ws_size,
                              hipStream_t stream) {
    const float* mo  = (const float*)d_in[0];
    const float* tg  = (const float*)d_in[1];
    const float* x0  = (const float*)d_in[2];
    const float* var = (const float*)d_in[3];
    float* out = (float*)d_out;

    float* ws_res = (float*)d_ws;           // NB floats (clamped residual term)
    float* ws_d   = ws_res + NB;            // NB floats (data-loss partials)

    darcy_wave_kernel<<<NB / 4, 256, 0, stream>>>(mo, tg, x0, var, ws_res, ws_d);
    darcy_final_kernel<<<1, 256, 0, stream>>>(ws_res, ws_d, out);
}